// Round 1
// baseline (703.466 us; speedup 1.0000x reference)
//
#include <hip/hip_runtime.h>
#include <cstdint>
#include <cstddef>

#define BATCH 256
#define NN 400
#define HH 256
#define TDIM 128
#define HALFD 64
#define OUTD 800
#define LCAP 96

// ---- K1: per-graph column scan: value-sum (degree feature), nnz count,
//          neighbor lists, dis = rsqrt(nnz+1), u = dis * degree ----
__global__ __launch_bounds__(512) void k_prep(
    const float* __restrict__ adj, float* __restrict__ dis,
    float* __restrict__ u, int* __restrict__ cnt,
    unsigned short* __restrict__ lists) {
  int b = blockIdx.x;
  int t = threadIdx.x;
  if (t >= NN) return;
  const float* col = adj + (size_t)b * NN * NN + t;
  unsigned short* lst = lists + ((size_t)b * NN + t) * LCAP;
  float vsum = 0.f;
  int c = 0;
#pragma unroll 4
  for (int i = 0; i < NN; ++i) {
    float v = col[(size_t)i * NN];
    if (v != 0.f) {
      vsum += v;
      if (c < LCAP) lst[c] = (unsigned short)i;
      ++c;
    }
  }
  float d = rsqrtf((float)c + 1.f);
  dis[b * NN + t] = d;
  u[b * NN + t] = d * vsum;
  cnt[b * NN + t] = (c < LCAP) ? c : LCAP;
}

// ---- K2: sinusoidal timestep embedding -> tproj[b,h] = temb[b,:] @ W1[1:,:]
__global__ __launch_bounds__(256) void k_temb(
    const float* __restrict__ times, const float* __restrict__ W1,
    float* __restrict__ tproj) {
  int b = blockIdx.x;
  int t = threadIdx.x;
  __shared__ float te[TDIM];
  if (t < HALFD) {
    float f = expf(-9.210340371976184f * (float)t / (float)(HALFD - 1));
    float arg = times[b] * f;
    te[t] = sinf(arg);
    te[t + HALFD] = cosf(arg);
  }
  __syncthreads();
  float acc = 0.f;
#pragma unroll 8
  for (int k = 0; k < TDIM; ++k) acc += te[k] * W1[(1 + k) * HH + t];
  tproj[b * HH + t] = acc;
}

// ---- K3: p_i = u_i + sum_{j in nbr(i)} u_j ; q_i = dis_i + sum dis_j ----
__global__ __launch_bounds__(512) void k_pq(
    const float* __restrict__ dis, const float* __restrict__ u,
    const int* __restrict__ cnt, const unsigned short* __restrict__ lists,
    float* __restrict__ p, float* __restrict__ q) {
  int b = blockIdx.x;
  int t = threadIdx.x;
  __shared__ float sd[NN];
  __shared__ float su[NN];
  for (int j = t; j < NN; j += 512) { sd[j] = dis[b * NN + j]; su[j] = u[b * NN + j]; }
  __syncthreads();
  if (t >= NN) return;
  int c = cnt[b * NN + t];
  const unsigned short* lst = lists + ((size_t)b * NN + t) * LCAP;
  float ps = su[t], qs = sd[t];
  for (int k = 0; k < c; ++k) { int j = lst[k]; ps += su[j]; qs += sd[j]; }
  p[b * NN + t] = ps;
  q[b * NN + t] = qs;
}

// ---- K4: y2 = dis ⊙ (g1 @ W2), g1 generated on the fly from (p,q,tproj).
//      Flattened M = CB*400 rows. 64x64 tile, 4x4 micro, K=256 in steps of 16.
__global__ __launch_bounds__(256) void k_gemm(
    const float* __restrict__ W2, const float* __restrict__ W1,
    const float* __restrict__ b1, const float* __restrict__ tproj,
    const float* __restrict__ dis, const float* __restrict__ p,
    const float* __restrict__ q, float* __restrict__ y2, int b0) {
  __shared__ __align__(16) float As[16][68];  // [k][m]
  __shared__ __align__(16) float Bs[16][68];  // [k][n]
  int t = threadIdx.x;
  int m0 = blockIdx.x * 64;  // chunk-local row base
  int n0 = blockIdx.y * 64;

  // A-generation mapping: thread -> (k_g, 4 rows at m_g)
  int k_g = t >> 4;          // 0..15
  int m_g = (t & 15) << 2;   // 0,4,..,60
  float dis4[4], p4[4], q4[4];
  const float* tp4[4];
#pragma unroll
  for (int c = 0; c < 4; ++c) {
    int r = m0 + m_g + c;
    int i = r % NN;
    int bg = b0 + r / NN;
    dis4[c] = dis[bg * NN + i];
    p4[c] = p[bg * NN + i];
    q4[c] = q[bg * NN + i];
    tp4[c] = tproj + bg * HH;
  }
  // B-load mapping
  int k_b = t >> 4;
  int n_b = (t & 15) << 2;

  int tx = t & 15;
  int ty = t >> 4;
  float acc[4][4] = {};

  for (int k0 = 0; k0 < HH; k0 += 16) {
    // generate A tile (g1 values) directly into LDS
    int k = k0 + k_g;
    float w0 = W1[k];
    float b1v = b1[k];
    float g[4];
#pragma unroll
    for (int c = 0; c < 4; ++c) {
      float tpv = tp4[c][k];
      g[c] = fmaxf(dis4[c] * (p4[c] * w0 + q4[c] * tpv) + b1v, 0.f);
    }
    *(float4*)(&As[k_g][m_g]) = make_float4(g[0], g[1], g[2], g[3]);
    // load B tile
    *(float4*)(&Bs[k_b][n_b]) = *(const float4*)(W2 + (size_t)(k0 + k_b) * HH + n0 + n_b);
    __syncthreads();
#pragma unroll
    for (int kk = 0; kk < 16; ++kk) {
      float4 av = *(const float4*)(&As[kk][ty * 4]);
      float4 bv = *(const float4*)(&Bs[kk][tx * 4]);
      acc[0][0] += av.x * bv.x; acc[0][1] += av.x * bv.y; acc[0][2] += av.x * bv.z; acc[0][3] += av.x * bv.w;
      acc[1][0] += av.y * bv.x; acc[1][1] += av.y * bv.y; acc[1][2] += av.y * bv.z; acc[1][3] += av.y * bv.w;
      acc[2][0] += av.z * bv.x; acc[2][1] += av.z * bv.y; acc[2][2] += av.z * bv.z; acc[2][3] += av.z * bv.w;
      acc[3][0] += av.w * bv.x; acc[3][1] += av.w * bv.y; acc[3][2] += av.w * bv.z; acc[3][3] += av.w * bv.w;
    }
    __syncthreads();
  }
  // epilogue: y2 = dis_row * acc
#pragma unroll
  for (int ii = 0; ii < 4; ++ii) {
    int rr = m0 + ty * 4 + ii;
    int i2 = rr % NN;
    int bg2 = b0 + rr / NN;
    float ds = dis[bg2 * NN + i2];
    float4 o = make_float4(ds * acc[ii][0], ds * acc[ii][1], ds * acc[ii][2], ds * acc[ii][3]);
    *(float4*)(y2 + (size_t)rr * HH + n0 + tx * 4) = o;
  }
}

// ---- K5: s2_i = y2_i + sum_{j in nbr(i)} y2_j ; g2 = relu(dis_i*s2 + b2) ----
__global__ __launch_bounds__(256) void k_spmm(
    const float* __restrict__ y2, const float* __restrict__ dis,
    const float* __restrict__ b2, const int* __restrict__ cnt,
    const unsigned short* __restrict__ lists, float* __restrict__ g2, int b0) {
  int bl = blockIdx.x;  // chunk-local graph
  int i = blockIdx.y;   // node
  int t = threadIdx.x;  // 0..255 = h
  int bg = b0 + bl;
  __shared__ unsigned short ls[LCAP];
  int c = cnt[bg * NN + i];
  if (t < LCAP && t < c) ls[t] = lists[((size_t)bg * NN + i) * LCAP + t];
  __syncthreads();
  const float* base = y2 + (size_t)bl * NN * HH;
  float acc = base[(size_t)i * HH + t];  // self loop
  for (int k = 0; k < c; ++k) {
    int j = ls[k];
    acc += base[(size_t)j * HH + t];
  }
  float gv = fmaxf(dis[bg * NN + i] * acc + b2[t], 0.f);
  g2[((size_t)bl * NN + i) * HH + t] = gv;
}

// ---- K6: pooled[b,h] = mean_i g2[b,i,h] ----
__global__ __launch_bounds__(256) void k_pool(
    const float* __restrict__ g2, float* __restrict__ pooled, int b0) {
  int bl = blockIdx.x;
  int t = threadIdx.x;
  const float* base = g2 + (size_t)bl * NN * HH;
  float acc = 0.f;
#pragma unroll 4
  for (int i = 0; i < NN; ++i) acc += base[(size_t)i * HH + t];
  pooled[(b0 + bl) * HH + t] = acc * (1.f / 400.f);
}

// ---- K7: logits = pooled @ Wlin + blin ----
__global__ __launch_bounds__(256) void k_out(
    const float* __restrict__ pooled, const float* __restrict__ Wlin,
    const float* __restrict__ blin, float* __restrict__ out) {
  int b = blockIdx.x;
  int t = threadIdx.x;
  __shared__ float ps[HH];
  ps[t] = pooled[b * HH + t];
  __syncthreads();
#pragma unroll
  for (int c = 0; c < 4; ++c) {
    int o = t + c * 256;
    if (o < OUTD) {
      float acc = blin[o];
#pragma unroll 8
      for (int h = 0; h < HH; ++h) acc += ps[h] * Wlin[h * OUTD + o];
      out[b * OUTD + o] = acc;
    }
  }
}

extern "C" void kernel_launch(void* const* d_in, const int* in_sizes, int n_in,
                              void* d_out, int out_size, void* d_ws, size_t ws_size,
                              hipStream_t stream) {
  const float* adj   = (const float*)d_in[0];
  const float* times = (const float*)d_in[1];
  const float* W1    = (const float*)d_in[2];
  const float* b1    = (const float*)d_in[3];
  const float* W2    = (const float*)d_in[4];
  const float* b2    = (const float*)d_in[5];
  const float* Wlin  = (const float*)d_in[6];
  const float* blin  = (const float*)d_in[7];
  float* out = (float*)d_out;

  char* ws = (char*)d_ws;
  size_t off = 0;
  auto alloc = [&](size_t bytes) -> void* {
    void* ptr = ws + off;
    off = (off + bytes + 255) & ~(size_t)255;
    return ptr;
  };
  float* dis    = (float*)alloc((size_t)BATCH * NN * 4);
  float* u      = (float*)alloc((size_t)BATCH * NN * 4);
  float* p      = (float*)alloc((size_t)BATCH * NN * 4);
  float* q      = (float*)alloc((size_t)BATCH * NN * 4);
  int* cnt      = (int*)alloc((size_t)BATCH * NN * 4);
  float* tproj  = (float*)alloc((size_t)BATCH * HH * 4);
  float* pooled = (float*)alloc((size_t)BATCH * HH * 4);
  unsigned short* lists = (unsigned short*)alloc((size_t)BATCH * NN * LCAP * 2);
  size_t small = off;

  int CB = 4;  // chunk of graphs processed per big-buffer round-trip
  const int cand[6] = {256, 128, 64, 32, 16, 8};
  for (int ci = 0; ci < 6; ++ci) {
    if (small + 2 * (size_t)cand[ci] * NN * HH * 4 <= ws_size) { CB = cand[ci]; break; }
  }
  float* y2 = (float*)alloc((size_t)CB * NN * HH * 4);
  float* g2 = (float*)alloc((size_t)CB * NN * HH * 4);

  k_prep<<<BATCH, 512, 0, stream>>>(adj, dis, u, cnt, lists);
  k_temb<<<BATCH, 256, 0, stream>>>(times, W1, tproj);
  k_pq<<<BATCH, 512, 0, stream>>>(dis, u, cnt, lists, p, q);

  for (int b0 = 0; b0 < BATCH; b0 += CB) {
    dim3 gg(CB * NN / 64, HH / 64);
    k_gemm<<<gg, 256, 0, stream>>>(W2, W1, b1, tproj, dis, p, q, y2, b0);
    dim3 gs(CB, NN);
    k_spmm<<<gs, 256, 0, stream>>>(y2, dis, b2, cnt, lists, g2, b0);
    k_pool<<<CB, 256, 0, stream>>>(g2, pooled, b0);
  }
  k_out<<<BATCH, 256, 0, stream>>>(pooled, Wlin, blin, out);
}

// Round 2
// 648.302 us; speedup vs baseline: 1.0851x; 1.0851x over previous
//
#include <hip/hip_runtime.h>
#include <cstdint>
#include <cstddef>

#define BATCH 256
#define NN 400
#define HH 256
#define TDIM 128
#define HALFD 64
#define OUTD 800
#define NSEG 8
#define SEGROWS 50
#define SEGCAP 16
#define W2PAD 264  // 256 + 8 bf16 pad -> 2-way-free LDS banks on ds_read_b128

using short8 = __attribute__((ext_vector_type(8))) short;
using f32x4  = __attribute__((ext_vector_type(4))) float;

__device__ __forceinline__ float bf2f(unsigned short h) {
  union { unsigned int u; float f; } c; c.u = ((unsigned int)h) << 16; return c.f;
}
__device__ __forceinline__ short f2bf_trunc(float x) {
  union { float f; unsigned int u; } c; c.f = x; return (short)(c.u >> 16);
}
__device__ __forceinline__ short f2bf_rne(float x) {
  union { float f; unsigned int u; } c; c.f = x;
  unsigned int r = c.u + 0x7FFFu + ((c.u >> 16) & 1u);
  return (short)(r >> 16);
}

// ---- K1: segmented column scan. Grid (B, NSEG). Each block scans 50 rows for
//      all 400 columns: per-(node,seg) neighbor list + count. Binary adj =>
//      degree == count.
__global__ __launch_bounds__(512) void k_prep(const float* __restrict__ adj,
    unsigned char* __restrict__ cseg, unsigned short* __restrict__ seglist) {
  int b = blockIdx.x, s = blockIdx.y, t = threadIdx.x;
  if (t >= NN) return;
  const float* p = adj + ((size_t)b * NN + s * SEGROWS) * NN + t;
  unsigned short* lst = seglist + (((size_t)b * NN + t) * NSEG + s) * SEGCAP;
  int c = 0;
#pragma unroll 5
  for (int i = 0; i < SEGROWS; ++i) {
    float v = p[(size_t)i * NN];
    if (v != 0.f) { if (c < SEGCAP) lst[c] = (unsigned short)(s * SEGROWS + i); ++c; }
  }
  cseg[((size_t)b * NN + t) * NSEG + s] = (unsigned char)(c < SEGCAP ? c : SEGCAP);
}

// ---- K2: tproj[b,h] = temb(times[b]) @ W1[1:,:]
__global__ __launch_bounds__(256) void k_temb(
    const float* __restrict__ times, const float* __restrict__ W1,
    float* __restrict__ tproj) {
  int b = blockIdx.x, t = threadIdx.x;
  __shared__ float te[TDIM];
  if (t < HALFD) {
    float f = expf(-9.210340371976184f * (float)t / (float)(HALFD - 1));
    float arg = times[b] * f;
    te[t] = sinf(arg);
    te[t + HALFD] = cosf(arg);
  }
  __syncthreads();
  float acc = 0.f;
#pragma unroll 8
  for (int k = 0; k < TDIM; ++k) acc += te[k] * W1[(1 + k) * HH + t];
  tproj[b * HH + t] = acc;
}

// ---- K3: dis = rsqrt(deg+1); pp = dis*(As@(dis*deg)); qq = dis*(As@dis)
__global__ __launch_bounds__(512) void k_pq(const unsigned char* __restrict__ cseg,
    const unsigned short* __restrict__ seglist, float* __restrict__ dis,
    float* __restrict__ pp, float* __restrict__ qq) {
  int b = blockIdx.x, t = threadIdx.x;
  __shared__ float sd[NN], su[NN];
  if (t < NN) {
    int deg = 0;
#pragma unroll
    for (int s = 0; s < NSEG; ++s) deg += cseg[((size_t)b * NN + t) * NSEG + s];
    float d = rsqrtf((float)deg + 1.f);
    sd[t] = d; su[t] = d * (float)deg;
  }
  __syncthreads();
  if (t >= NN) return;
  float ps = su[t], qs = sd[t];  // self loop
#pragma unroll
  for (int s = 0; s < NSEG; ++s) {
    int c = cseg[((size_t)b * NN + t) * NSEG + s];
    const unsigned short* lst = seglist + (((size_t)b * NN + t) * NSEG + s) * SEGCAP;
    for (int k = 0; k < c; ++k) { int j = lst[k]; ps += su[j]; qs += sd[j]; }
  }
  float d = sd[t];
  dis[b * NN + t] = d;
  pp[b * NN + t] = d * ps;
  qq[b * NN + t] = d * qs;
}

// ---- K4: W2 -> bf16 transposed padded [256 n][264 k]
__global__ __launch_bounds__(256) void k_w2t(const float* __restrict__ W2,
                                             short* __restrict__ W2Tg) {
  int n = blockIdx.x, k = threadIdx.x;
  W2Tg[n * W2PAD + k] = f2bf_rne(W2[k * HH + n]);
}

// ---- K5: y2 = dis ⊙ (g1 @ W2) via bf16 MFMA. g1 generated on the fly.
//      Block: 8 waves, 128 rows, 128 cols (half of N). W2T half in LDS.
__global__ __launch_bounds__(512) void k_gemm(const short* __restrict__ W2Tg,
    const float* __restrict__ W1, const float* __restrict__ b1,
    const float* __restrict__ tproj, const float* __restrict__ dis,
    const float* __restrict__ pp, const float* __restrict__ qq,
    short* __restrict__ y2, int b0) {
  extern __shared__ short w2t[];  // [128][264] bf16 = 67584 B; reused as bounce buf
  int t = threadIdx.x;
  int wv = t >> 6, lane = t & 63, l15 = lane & 15, l4 = lane >> 4;
  int ny = blockIdx.y;

  // stage W2T half into LDS (16B chunks, coalesced, linear)
  {
    const short* gsrc = W2Tg + (size_t)ny * 128 * W2PAD;
#pragma unroll
    for (int r = 0; r < 9; ++r) {
      int idx = r * 512 + t;
      if (idx < 128 * W2PAD / 8) *(short8*)(w2t + idx * 8) = *(const short8*)(gsrc + idx * 8);
    }
  }

  int grow = b0 * NN + blockIdx.x * 128;   // global flattened row base
  int arow = grow + wv * 16 + l15;         // this lane's A row
  int gph = arow / NN;
  float ppv = pp[arow], qqv = qq[arow];
  const float* tpr = tproj + gph * HH;

  f32x4 acc[8];
#pragma unroll
  for (int f = 0; f < 8; ++f) acc[f] = (f32x4){0.f, 0.f, 0.f, 0.f};

  __syncthreads();

#pragma unroll 2
  for (int k0 = 0; k0 < 8; ++k0) {
    int kk = k0 * 32 + l4 * 8;
    float4 w1a = *(const float4*)(W1 + kk), w1b = *(const float4*)(W1 + kk + 4);
    float4 b1a = *(const float4*)(b1 + kk), b1b = *(const float4*)(b1 + kk + 4);
    float4 tpa = *(const float4*)(tpr + kk), tpb = *(const float4*)(tpr + kk + 4);
    short8 af;
    af[0] = f2bf_trunc(fmaxf(ppv * w1a.x + qqv * tpa.x + b1a.x, 0.f));
    af[1] = f2bf_trunc(fmaxf(ppv * w1a.y + qqv * tpa.y + b1a.y, 0.f));
    af[2] = f2bf_trunc(fmaxf(ppv * w1a.z + qqv * tpa.z + b1a.z, 0.f));
    af[3] = f2bf_trunc(fmaxf(ppv * w1a.w + qqv * tpa.w + b1a.w, 0.f));
    af[4] = f2bf_trunc(fmaxf(ppv * w1b.x + qqv * tpb.x + b1b.x, 0.f));
    af[5] = f2bf_trunc(fmaxf(ppv * w1b.y + qqv * tpb.y + b1b.y, 0.f));
    af[6] = f2bf_trunc(fmaxf(ppv * w1b.z + qqv * tpb.z + b1b.z, 0.f));
    af[7] = f2bf_trunc(fmaxf(ppv * w1b.w + qqv * tpb.w + b1b.w, 0.f));
#pragma unroll
    for (int f = 0; f < 8; ++f) {
      short8 bf = *(const short8*)(w2t + (f * 16 + l15) * W2PAD + kk);
      acc[f] = __builtin_amdgcn_mfma_f32_16x16x32_bf16(af, bf, acc[f], 0, 0, 0);
    }
  }

  // epilogue: scale by dis(row), bf16, bounce through LDS for coalesced stores
  float dis4[4];
#pragma unroll
  for (int rr = 0; rr < 4; ++rr) dis4[rr] = dis[grow + wv * 16 + l4 * 4 + rr];

  __syncthreads();  // all waves done reading w2t
  short* bb = w2t;  // reuse as [128][132] bf16 bounce
#pragma unroll
  for (int f = 0; f < 8; ++f) {
#pragma unroll
    for (int rr = 0; rr < 4; ++rr) {
      int row = wv * 16 + l4 * 4 + rr;
      bb[row * 132 + f * 16 + l15] = f2bf_trunc(dis4[rr] * acc[f][rr]);
    }
  }
  __syncthreads();
  int lrow = blockIdx.x * 128;
#pragma unroll
  for (int p2 = 0; p2 < 16; ++p2) {
    int idx = p2 * 512 + t;
    int row = idx >> 6, w = idx & 63;
    unsigned int v = *(const unsigned int*)(bb + row * 132 + w * 2);
    *(unsigned int*)(y2 + ((size_t)(lrow + row) * HH + ny * 128 + w * 2)) = v;
  }
}

// ---- K6: fused SpMM + relu + mean-pool. Block = (graph, 64-col quarter).
//      y2 quarter staged in LDS bf16; g2 never materialized.
__global__ __launch_bounds__(256) void k_spmm_pool(const short* __restrict__ y2,
    const float* __restrict__ dis, const float* __restrict__ b2,
    const unsigned char* __restrict__ cseg, const unsigned short* __restrict__ seglist,
    float* __restrict__ pooled, int b0) {
  int bl = blockIdx.x, q = blockIdx.y, t = threadIdx.x;
  int bg = b0 + bl;
  __shared__ __align__(16) unsigned int smem[NN * 34];  // 400 rows * 68 bf16 = 54400 B
  // stage: 8 rows/pass (uint = 2 bf16 per lane), 50 passes, conflict-free writes
  {
    int w32 = t & 31, r8 = t >> 5;
    for (int pass = 0; pass < 50; ++pass) {
      int i = pass * 8 + r8;
      unsigned int v = *(const unsigned int*)(y2 + ((size_t)(bl * NN + i) * HH + q * 64 + w32 * 2));
      smem[i * 34 + w32] = v;
    }
  }
  __syncthreads();
  int w = t & 31, g = t >> 5;
  float b20 = b2[q * 64 + 2 * w], b21 = b2[q * 64 + 2 * w + 1];
  float p0 = 0.f, p1 = 0.f;
  for (int m = 0; m < SEGROWS; ++m) {
    int i = g + 8 * m;
    unsigned int v = smem[i * 34 + w];  // self loop
    float a0 = bf2f((unsigned short)v), a1 = bf2f((unsigned short)(v >> 16));
    const unsigned char* cb = cseg + ((size_t)bg * NN + i) * NSEG;
    const unsigned short* lb = seglist + ((size_t)bg * NN + i) * NSEG * SEGCAP;
#pragma unroll
    for (int s = 0; s < NSEG; ++s) {
      int c = cb[s];
      const unsigned short* lst = lb + s * SEGCAP;
      for (int k = 0; k < c; ++k) {
        int j = lst[k];
        unsigned int vv = smem[j * 34 + w];
        a0 += bf2f((unsigned short)vv); a1 += bf2f((unsigned short)(vv >> 16));
      }
    }
    float dsi = dis[bg * NN + i];
    p0 += fmaxf(dsi * a0 + b20, 0.f);
    p1 += fmaxf(dsi * a1 + b21, 0.f);
  }
  __syncthreads();
  float* red = (float*)smem;
  red[g * 64 + 2 * w] = p0;
  red[g * 64 + 2 * w + 1] = p1;
  __syncthreads();
  if (t < 64) {
    float sum = 0.f;
#pragma unroll
    for (int gg = 0; gg < 8; ++gg) sum += red[gg * 64 + t];
    pooled[bg * HH + q * 64 + t] = sum * (1.f / 400.f);
  }
}

// ---- K7: logits = pooled @ Wlin + blin
__global__ __launch_bounds__(256) void k_out(
    const float* __restrict__ pooled, const float* __restrict__ Wlin,
    const float* __restrict__ blin, float* __restrict__ out) {
  int b = blockIdx.x, t = threadIdx.x;
  __shared__ float ps[HH];
  ps[t] = pooled[b * HH + t];
  __syncthreads();
#pragma unroll
  for (int c = 0; c < 4; ++c) {
    int o = t + c * 256;
    if (o < OUTD) {
      float acc = blin[o];
#pragma unroll 8
      for (int h = 0; h < HH; ++h) acc += ps[h] * Wlin[h * OUTD + o];
      out[b * OUTD + o] = acc;
    }
  }
}

extern "C" void kernel_launch(void* const* d_in, const int* in_sizes, int n_in,
                              void* d_out, int out_size, void* d_ws, size_t ws_size,
                              hipStream_t stream) {
  const float* adj   = (const float*)d_in[0];
  const float* times = (const float*)d_in[1];
  const float* W1    = (const float*)d_in[2];
  const float* b1    = (const float*)d_in[3];
  const float* W2    = (const float*)d_in[4];
  const float* b2    = (const float*)d_in[5];
  const float* Wlin  = (const float*)d_in[6];
  const float* blin  = (const float*)d_in[7];
  float* out = (float*)d_out;

  char* ws = (char*)d_ws;
  size_t off = 0;
  auto alloc = [&](size_t bytes) -> void* {
    void* ptr = ws + off;
    off = (off + bytes + 255) & ~(size_t)255;
    return ptr;
  };
  float* dis    = (float*)alloc((size_t)BATCH * NN * 4);
  float* pp     = (float*)alloc((size_t)BATCH * NN * 4);
  float* qq     = (float*)alloc((size_t)BATCH * NN * 4);
  float* tproj  = (float*)alloc((size_t)BATCH * HH * 4);
  float* pooled = (float*)alloc((size_t)BATCH * HH * 4);
  unsigned char*  cseg    = (unsigned char*)alloc((size_t)BATCH * NN * NSEG);
  unsigned short* seglist = (unsigned short*)alloc((size_t)BATCH * NN * NSEG * SEGCAP * 2);
  short* W2Tg = (short*)alloc((size_t)HH * W2PAD * 2);
  size_t small = off;

  int CB = 8;
  const int cand[6] = {256, 128, 64, 32, 16, 8};
  for (int ci = 0; ci < 6; ++ci) {
    if (small + (size_t)cand[ci] * NN * HH * 2 <= ws_size) { CB = cand[ci]; break; }
  }
  short* y2 = (short*)alloc((size_t)CB * NN * HH * 2);

  k_prep<<<dim3(BATCH, NSEG), 512, 0, stream>>>(adj, cseg, seglist);
  k_temb<<<BATCH, 256, 0, stream>>>(times, W1, tproj);
  k_pq<<<BATCH, 512, 0, stream>>>(cseg, seglist, dis, pp, qq);
  k_w2t<<<HH, 256, 0, stream>>>(W2, W2Tg);

  for (int b0 = 0; b0 < BATCH; b0 += CB) {
    dim3 gg(CB * NN / 128, 2);
    k_gemm<<<gg, 512, 128 * W2PAD * 2, stream>>>(W2Tg, W1, b1, tproj, dis, pp, qq, y2, b0);
    dim3 gs(CB, 4);
    k_spmm_pool<<<gs, 256, 0, stream>>>(y2, dis, b2, cseg, seglist, pooled, b0);
  }
  k_out<<<BATCH, 256, 0, stream>>>(pooled, Wlin, blin, out);
}

// Round 3
// 336.813 us; speedup vs baseline: 2.0886x; 1.9248x over previous
//
#include <hip/hip_runtime.h>
#include <cstdint>
#include <cstddef>

#define BATCH 256
#define NN 400
#define HH 256
#define TDIM 128
#define HALFD 64
#define OUTD 800
#define KP 416        // padded node/K dimension (13 x 32)
#define W2PAD 264     // W2T LDS row stride (bf16)
#define BTS 40        // y2T LDS tile row stride (bf16): 80B rows, 16B aligned, 2-way banks

using short8   = __attribute__((ext_vector_type(8))) short;
using short4v  = __attribute__((ext_vector_type(4))) short;
using ushort4v = __attribute__((ext_vector_type(4))) unsigned short;
using f32x4    = __attribute__((ext_vector_type(4))) float;

__device__ __forceinline__ float bf2f(unsigned short h) {
  union { unsigned int u; float f; } c; c.u = ((unsigned int)h) << 16; return c.f;
}
__device__ __forceinline__ short f2bf_trunc(float x) {
  union { float f; unsigned int u; } c; c.f = x; return (short)(c.u >> 16);
}
__device__ __forceinline__ short f2bf_rne(float x) {
  union { float f; unsigned int u; } c; c.f = x;
  unsigned int r = c.u + 0x7FFFu + ((c.u >> 16) & 1u);
  return (short)(r >> 16);
}

// ---- K1: adj -> As bf16 [CB][400][416] (binary + self loop, K-pad zeroed),
//          dis = rsqrt(cnt+1), dd = dis*cnt.  Grid (CB, 25), 4 waves x 4 rows.
__global__ __launch_bounds__(256) void k_prep(const float* __restrict__ adj,
    short* __restrict__ As, float* __restrict__ dis, float* __restrict__ dd, int b0) {
  int bl = blockIdx.x, bg = b0 + bl;
  int rbase = blockIdx.y * 16;
  int wv = threadIdx.x >> 6, lane = threadIdx.x & 63;
#pragma unroll
  for (int rr = 0; rr < 4; ++rr) {
    int i = rbase + wv * 4 + rr;
    const float* arow = adj + ((size_t)bg * NN + i) * NN;
    short* orow = As + ((size_t)bl * NN + i) * KP;
    int cnt = 0;
#pragma unroll
    for (int c = 0; c < 4; ++c) {
      int j2 = c * 64 + lane;  // float2 chunk index; j = 2*j2
      if (j2 < 200) {
        float2 v = *(const float2*)(arow + 2 * j2);
        int j0 = 2 * j2;
        unsigned int h0 = (v.x != 0.f) ? 0x3F80u : 0u;
        unsigned int h1 = (v.y != 0.f) ? 0x3F80u : 0u;
        cnt += (v.x != 0.f) + (v.y != 0.f);
        if (j0 == i) h0 = 0x3F80u;       // self loop
        if (j0 + 1 == i) h1 = 0x3F80u;
        *(unsigned int*)(orow + j0) = (h1 << 16) | h0;
      }
    }
    if (lane < 8) *(unsigned int*)(orow + 400 + 2 * lane) = 0u;  // K pad
#pragma unroll
    for (int s = 32; s; s >>= 1) cnt += __shfl_xor(cnt, s);
    if (lane == 0) {
      float d = rsqrtf((float)cnt + 1.f);
      dis[bg * NN + i] = d;
      dd[bg * NN + i] = d * (float)cnt;
    }
  }
}

// ---- K2: tproj[b,h] = temb(times[b]) @ W1[1:,:]
__global__ __launch_bounds__(256) void k_temb(
    const float* __restrict__ times, const float* __restrict__ W1,
    float* __restrict__ tproj) {
  int b = blockIdx.x, t = threadIdx.x;
  __shared__ float te[TDIM];
  if (t < HALFD) {
    float f = expf(-9.210340371976184f * (float)t / (float)(HALFD - 1));
    float arg = times[b] * f;
    te[t] = sinf(arg);
    te[t + HALFD] = cosf(arg);
  }
  __syncthreads();
  float acc = 0.f;
#pragma unroll 8
  for (int k = 0; k < TDIM; ++k) acc += te[k] * W1[(1 + k) * HH + t];
  tproj[b * HH + t] = acc;
}

// ---- K3: dense matvec over As: pp = dis_i*(As@dd), qq = dis_i*(As@dis)
//      Grid (CB), 8 waves x 50 rows.
__global__ __launch_bounds__(512) void k_pq(const short* __restrict__ As,
    const float* __restrict__ dis, const float* __restrict__ dd,
    float* __restrict__ pp, float* __restrict__ qq, int b0) {
  int bl = blockIdx.x, bg = b0 + bl;
  int t = threadIdx.x, wv = t >> 6, lane = t & 63;
  __shared__ float sd[NN], su[NN];
  for (int j = t; j < NN; j += 512) { sd[j] = dis[bg * NN + j]; su[j] = dd[bg * NN + j]; }
  __syncthreads();
  for (int r = 0; r < 50; ++r) {
    int i = wv * 50 + r;
    const short* rowp = As + ((size_t)bl * NN + i) * KP;
    float ps = 0.f, qs = 0.f;
    {
      ushort4v v = *(const ushort4v*)(rowp + 4 * lane);
#pragma unroll
      for (int e = 0; e < 4; ++e)
        if (v[e]) { ps += su[4 * lane + e]; qs += sd[4 * lane + e]; }
    }
    if (lane < 36) {
      ushort4v v = *(const ushort4v*)(rowp + 256 + 4 * lane);
#pragma unroll
      for (int e = 0; e < 4; ++e)
        if (v[e]) { ps += su[256 + 4 * lane + e]; qs += sd[256 + 4 * lane + e]; }
    }
#pragma unroll
    for (int s = 32; s; s >>= 1) { ps += __shfl_xor(ps, s); qs += __shfl_xor(qs, s); }
    if (lane == 0) {
      float d = sd[i];
      pp[bg * NN + i] = d * ps;
      qq[bg * NN + i] = d * qs;
    }
  }
}

// ---- K4: W2 -> bf16 transposed padded [256 n][264 k]
__global__ __launch_bounds__(256) void k_w2t(const float* __restrict__ W2,
                                             short* __restrict__ W2Tg) {
  int n = blockIdx.x, k = threadIdx.x;
  W2Tg[n * W2PAD + k] = f2bf_rne(W2[k * HH + n]);
}

// ---- K5: y2T[n][m] = dis_m * (g1 @ W2)[m][n], g1 on the fly. Per-graph
//      80-row tiles, 5 waves, 128-col halves. Output TRANSPOSED (k-major).
__global__ __launch_bounds__(320) void k_gemm(const short* __restrict__ W2Tg,
    const float* __restrict__ W1, const float* __restrict__ b1,
    const float* __restrict__ tproj, const float* __restrict__ dis,
    const float* __restrict__ pp, const float* __restrict__ qq,
    short* __restrict__ y2T, int b0) {
  extern __shared__ short lds[];  // 128*264*2 = 67584 B; reused as bounce [128][88]
  int t = threadIdx.x;
  int wv = t >> 6, lane = t & 63, l15 = lane & 15, l4 = lane >> 4;
  int bl = blockIdx.x / 5, mt = blockIdx.x % 5;
  int ny = blockIdx.y;
  int bg = b0 + bl;
  int m0 = mt * 80;

  {
    const short* gsrc = W2Tg + (size_t)ny * 128 * W2PAD;
#pragma unroll
    for (int r = 0; r < 14; ++r) {
      int idx = r * 320 + t;
      if (idx < 128 * W2PAD / 8) *(short8*)(lds + idx * 8) = *(const short8*)(gsrc + idx * 8);
    }
  }

  int arow = m0 + wv * 16 + l15;
  int gnode = bg * NN + arow;
  float ppv = pp[gnode], qqv = qq[gnode];
  const float* tpr = tproj + bg * HH;

  f32x4 acc[8];
#pragma unroll
  for (int f = 0; f < 8; ++f) acc[f] = (f32x4){0.f, 0.f, 0.f, 0.f};

  __syncthreads();

#pragma unroll 2
  for (int k0 = 0; k0 < 8; ++k0) {
    int kk = k0 * 32 + l4 * 8;
    float4 w1a = *(const float4*)(W1 + kk), w1b = *(const float4*)(W1 + kk + 4);
    float4 b1a = *(const float4*)(b1 + kk), b1b = *(const float4*)(b1 + kk + 4);
    float4 tpa = *(const float4*)(tpr + kk), tpb = *(const float4*)(tpr + kk + 4);
    short8 af;
    af[0] = f2bf_trunc(fmaxf(ppv * w1a.x + qqv * tpa.x + b1a.x, 0.f));
    af[1] = f2bf_trunc(fmaxf(ppv * w1a.y + qqv * tpa.y + b1a.y, 0.f));
    af[2] = f2bf_trunc(fmaxf(ppv * w1a.z + qqv * tpa.z + b1a.z, 0.f));
    af[3] = f2bf_trunc(fmaxf(ppv * w1a.w + qqv * tpa.w + b1a.w, 0.f));
    af[4] = f2bf_trunc(fmaxf(ppv * w1b.x + qqv * tpb.x + b1b.x, 0.f));
    af[5] = f2bf_trunc(fmaxf(ppv * w1b.y + qqv * tpb.y + b1b.y, 0.f));
    af[6] = f2bf_trunc(fmaxf(ppv * w1b.z + qqv * tpb.z + b1b.z, 0.f));
    af[7] = f2bf_trunc(fmaxf(ppv * w1b.w + qqv * tpb.w + b1b.w, 0.f));
#pragma unroll
    for (int f = 0; f < 8; ++f) {
      short8 bf = *(const short8*)(lds + (f * 16 + l15) * W2PAD + kk);
      acc[f] = __builtin_amdgcn_mfma_f32_16x16x32_bf16(af, bf, acc[f], 0, 0, 0);
    }
  }

  float dis4[4];
#pragma unroll
  for (int rr = 0; rr < 4; ++rr) dis4[rr] = dis[bg * NN + m0 + wv * 16 + l4 * 4 + rr];

  __syncthreads();  // all waves done reading W2T
  short* bb = lds;  // [128 n][88 m] bf16 bounce (transposed)
#pragma unroll
  for (int f = 0; f < 8; ++f) {
    short4v pk;
#pragma unroll
    for (int rr = 0; rr < 4; ++rr) pk[rr] = f2bf_trunc(dis4[rr] * acc[f][rr]);
    *(short4v*)(&bb[(f * 16 + l15) * 88 + wv * 16 + l4 * 4]) = pk;
  }
  __syncthreads();
  short* ybase = y2T + (size_t)bl * HH * KP + (size_t)ny * 128 * KP + m0;
#pragma unroll
  for (int r = 0; r < 4; ++r) {
    int idx = r * 320 + t;  // 1280 chunks of 16B
    int n = idx / 10, c = idx % 10;
    short8 v = *(const short8*)(&bb[n * 88 + c * 8]);
    *(short8*)(ybase + (size_t)n * KP + c * 8) = v;
  }
}

// ---- K5b: zero y2T K-pad rows [*, *, 400:416]
__global__ __launch_bounds__(256) void k_zpad(short* __restrict__ y2T) {
  int bl = blockIdx.x, t = threadIdx.x;
  short8 z = {};
  *(short8*)(y2T + (size_t)bl * HH * KP + (size_t)t * KP + 400) = z;
  *(short8*)(y2T + (size_t)bl * HH * KP + (size_t)t * KP + 408) = z;
}

// ---- K6: fused aggregation GEMM + relu + pool:
//      C[m][n] = sum_k As[m][k] * y2T[n][k]  (bf16 MFMA, As binary = exact)
//      poolP[mt][b][n] = sum_{valid m} relu(dis_m * C + b2[n])
//      Grid (CB, 4): 128 rows/block, 4 waves x (2x16 rows), N=256 full.
__global__ __launch_bounds__(256) void k_agg(const short* __restrict__ As,
    const short* __restrict__ y2T, const float* __restrict__ dis,
    const float* __restrict__ b2, float* __restrict__ poolP, int b0) {
  __shared__ short bt[2][256 * BTS];  // 2 x 20480 B
  __shared__ float pool[4][256];
  int t = threadIdx.x, wv = t >> 6, lane = t & 63, l15 = lane & 15, l4 = lane >> 4;
  int bl = blockIdx.x, mt = blockIdx.y, bg = b0 + bl;
  int mbase = mt * 128;
  const short* y2g = y2T + (size_t)bl * HH * KP;
  const short* asg = As + (size_t)bl * NN * KP;

#pragma unroll
  for (int i = 0; i < 4; ++i) {  // stage ks=0
    int idx = i * 256 + t, n = idx >> 2, c = idx & 3;
    *(short8*)(&bt[0][n * BTS + c * 8]) = *(const short8*)(y2g + (size_t)n * KP + c * 8);
  }

  f32x4 acc[2][16];
#pragma unroll
  for (int mf = 0; mf < 2; ++mf)
#pragma unroll
    for (int nf = 0; nf < 16; ++nf) acc[mf][nf] = (f32x4){0.f, 0.f, 0.f, 0.f};

  int buf = 0;
  for (int ks = 0; ks < 13; ++ks) {
    __syncthreads();
    if (ks < 12) {
      int ko = (ks + 1) * 32;
#pragma unroll
      for (int i = 0; i < 4; ++i) {
        int idx = i * 256 + t, n = idx >> 2, c = idx & 3;
        *(short8*)(&bt[buf ^ 1][n * BTS + c * 8]) =
            *(const short8*)(y2g + (size_t)n * KP + ko + c * 8);
      }
    }
    int k0 = ks * 32;
    short8 af[2];
#pragma unroll
    for (int mf = 0; mf < 2; ++mf) {
      int m = mbase + wv * 32 + mf * 16 + l15;
      short8 a = {};
      if (m < NN) a = *(const short8*)(asg + (size_t)m * KP + k0 + l4 * 8);
      af[mf] = a;
    }
#pragma unroll
    for (int nf = 0; nf < 16; ++nf) {
      short8 bf = *(const short8*)(&bt[buf][(nf * 16 + l15) * BTS + l4 * 8]);
      acc[0][nf] = __builtin_amdgcn_mfma_f32_16x16x32_bf16(af[0], bf, acc[0][nf], 0, 0, 0);
      acc[1][nf] = __builtin_amdgcn_mfma_f32_16x16x32_bf16(af[1], bf, acc[1][nf], 0, 0, 0);
    }
    buf ^= 1;
  }

  // epilogue: relu(dis_m * c + b2[n]), column-sum over rows, reduce l4 groups
#pragma unroll
  for (int nf = 0; nf < 16; ++nf) {
    float b2v = b2[nf * 16 + l15];
    float s = 0.f;
#pragma unroll
    for (int mf = 0; mf < 2; ++mf) {
      int mrow0 = mbase + wv * 32 + mf * 16;
      if (mrow0 < NN) {
        float4 d4 = *(const float4*)(dis + bg * NN + mrow0 + l4 * 4);
        s += fmaxf(d4.x * acc[mf][nf][0] + b2v, 0.f)
           + fmaxf(d4.y * acc[mf][nf][1] + b2v, 0.f)
           + fmaxf(d4.z * acc[mf][nf][2] + b2v, 0.f)
           + fmaxf(d4.w * acc[mf][nf][3] + b2v, 0.f);
      }
    }
    s += __shfl_xor(s, 16);
    s += __shfl_xor(s, 32);
    if (l4 == 0) pool[wv][nf * 16 + l15] = s;
  }
  __syncthreads();
  float s = pool[0][t] + pool[1][t] + pool[2][t] + pool[3][t];
  poolP[((size_t)mt * BATCH + bg) * HH + t] = s;
}

// ---- K7: logits = (sum_mt poolP / 400) @ Wlin + blin
__global__ __launch_bounds__(256) void k_out(
    const float* __restrict__ poolP, const float* __restrict__ Wlin,
    const float* __restrict__ blin, float* __restrict__ out) {
  int b = blockIdx.x, t = threadIdx.x;
  __shared__ float ps[HH];
  ps[t] = (poolP[(0 * BATCH + b) * HH + t] + poolP[(1 * BATCH + b) * HH + t] +
           poolP[(2 * BATCH + b) * HH + t] + poolP[(3 * BATCH + b) * HH + t]) * (1.f / 400.f);
  __syncthreads();
#pragma unroll
  for (int c = 0; c < 4; ++c) {
    int o = t + c * 256;
    if (o < OUTD) {
      float acc = blin[o];
#pragma unroll 8
      for (int h = 0; h < HH; ++h) acc += ps[h] * Wlin[h * OUTD + o];
      out[b * OUTD + o] = acc;
    }
  }
}

extern "C" void kernel_launch(void* const* d_in, const int* in_sizes, int n_in,
                              void* d_out, int out_size, void* d_ws, size_t ws_size,
                              hipStream_t stream) {
  const float* adj   = (const float*)d_in[0];
  const float* times = (const float*)d_in[1];
  const float* W1    = (const float*)d_in[2];
  const float* b1    = (const float*)d_in[3];
  const float* W2    = (const float*)d_in[4];
  const float* b2    = (const float*)d_in[5];
  const float* Wlin  = (const float*)d_in[6];
  const float* blin  = (const float*)d_in[7];
  float* out = (float*)d_out;

  char* ws = (char*)d_ws;
  size_t off = 0;
  auto alloc = [&](size_t bytes) -> void* {
    void* ptr = ws + off;
    off = (off + bytes + 255) & ~(size_t)255;
    return ptr;
  };
  float* dis    = (float*)alloc((size_t)BATCH * NN * 4);
  float* dd     = (float*)alloc((size_t)BATCH * NN * 4);
  float* pp     = (float*)alloc((size_t)BATCH * NN * 4);
  float* qq     = (float*)alloc((size_t)BATCH * NN * 4);
  float* tproj  = (float*)alloc((size_t)BATCH * HH * 4);
  float* poolP  = (float*)alloc((size_t)4 * BATCH * HH * 4);
  short* W2Tg   = (short*)alloc((size_t)HH * W2PAD * 2);
  size_t small = off;

  int CB = 8;
  const int cand[6] = {256, 128, 64, 32, 16, 8};
  size_t per_graph = ((size_t)NN * KP + (size_t)HH * KP) * 2;
  for (int ci = 0; ci < 6; ++ci) {
    if (small + (size_t)cand[ci] * per_graph + 512 <= ws_size) { CB = cand[ci]; break; }
  }
  short* As  = (short*)alloc((size_t)CB * NN * KP * 2);
  short* y2T = (short*)alloc((size_t)CB * HH * KP * 2);

  k_temb<<<BATCH, 256, 0, stream>>>(times, W1, tproj);
  k_w2t<<<HH, 256, 0, stream>>>(W2, W2Tg);

  for (int b0 = 0; b0 < BATCH; b0 += CB) {
    k_prep<<<dim3(CB, 25), 256, 0, stream>>>(adj, As, dis, dd, b0);
    k_pq<<<CB, 512, 0, stream>>>(As, dis, dd, pp, qq, b0);
    k_gemm<<<dim3(CB * 5, 2), 320, 128 * W2PAD * 2, stream>>>(
        W2Tg, W1, b1, tproj, dis, pp, qq, y2T, b0);
    k_zpad<<<CB, 256, 0, stream>>>(y2T);
    k_agg<<<dim3(CB, 4), 256, 0, stream>>>(As, y2T, dis, b2, poolP, b0);
  }
  k_out<<<BATCH, 256, 0, stream>>>(poolP, Wlin, blin, out);
}

// Round 4
// 175.063 us; speedup vs baseline: 4.0184x; 1.9240x over previous
//
#include <hip/hip_runtime.h>
#include <cstdint>
#include <cstddef>

#define BATCH 256
#define NN 400
#define HH 256
#define TDIM 128
#define HALFD 64
#define OUTD 800
#define KP 416        // padded node/K dimension (13 x 32)
#define BITW 16       // u32 words per bitmap row (13 used, 64B padded)
#define W2PAD 264     // W2T LDS row stride (bf16)

using short8   = __attribute__((ext_vector_type(8))) short;
using short4v  = __attribute__((ext_vector_type(4))) short;
using f32x4    = __attribute__((ext_vector_type(4))) float;

__device__ __forceinline__ short f2bf_trunc(float x) {
  union { float f; unsigned int u; } c; c.f = x; return (short)(c.u >> 16);
}
__device__ __forceinline__ short f2bf_rne(float x) {
  union { float f; unsigned int u; } c; c.f = x;
  unsigned int r = c.u + 0x7FFFu + ((c.u >> 16) & 1u);
  return (short)(r >> 16);
}

// ---- K1: adj -> bitmap [CB][400][16 u32] (binary + self loop), dis, dd.
//      Grid (CB, 25), 4 waves x 4 rows; lane l covers cols 8l..8l+7.
__global__ __launch_bounds__(256) void k_prep(const float* __restrict__ adj,
    unsigned int* __restrict__ bits, float* __restrict__ dis,
    float* __restrict__ dd, int b0) {
  int bl = blockIdx.x, bg = b0 + bl;
  int rbase = blockIdx.y * 16;
  int wv = threadIdx.x >> 6, lane = threadIdx.x & 63;
#pragma unroll
  for (int rr = 0; rr < 4; ++rr) {
    int i = rbase + wv * 4 + rr;
    const float* arow = adj + ((size_t)bg * NN + i) * NN;
    unsigned int b8 = 0; int c = 0;
    if (lane < 50) {
      float4 v0 = *(const float4*)(arow + 8 * lane);
      float4 v1 = *(const float4*)(arow + 8 * lane + 4);
      b8 = (v0.x != 0.f ? 1u : 0u) | (v0.y != 0.f ? 2u : 0u) |
           (v0.z != 0.f ? 4u : 0u) | (v0.w != 0.f ? 8u : 0u) |
           (v1.x != 0.f ? 16u : 0u) | (v1.y != 0.f ? 32u : 0u) |
           (v1.z != 0.f ? 64u : 0u) | (v1.w != 0.f ? 128u : 0u);
      c = __popc(b8);
      if ((i >> 3) == lane) b8 |= 1u << (i & 7);  // self loop
    }
    int cs = c;
#pragma unroll
    for (int s = 32; s; s >>= 1) cs += __shfl_xor(cs, s);
    // pack 4 bytes -> u32 via shfl (word w = bytes 4w..4w+3, LE => bit b = col 32w+b)
    unsigned int p0 = (unsigned int)__shfl((int)b8, 4 * lane);
    unsigned int p1 = (unsigned int)__shfl((int)b8, 4 * lane + 1);
    unsigned int p2 = (unsigned int)__shfl((int)b8, 4 * lane + 2);
    unsigned int p3 = (unsigned int)__shfl((int)b8, 4 * lane + 3);
    if (lane < BITW)
      bits[((size_t)bl * NN + i) * BITW + lane] =
          (lane < 13) ? (p0 | (p1 << 8) | (p2 << 16) | (p3 << 24)) : 0u;
    if (lane == 0) {
      float d = rsqrtf((float)cs + 1.f);
      dis[bg * NN + i] = d;
      dd[bg * NN + i] = d * (float)cs;
    }
  }
}

// ---- K2: tproj[b,h] = temb(times[b]) @ W1[1:,:]
__global__ __launch_bounds__(256) void k_temb(
    const float* __restrict__ times, const float* __restrict__ W1,
    float* __restrict__ tproj) {
  int b = blockIdx.x, t = threadIdx.x;
  __shared__ float te[TDIM];
  if (t < HALFD) {
    float f = expf(-9.210340371976184f * (float)t / (float)(HALFD - 1));
    float arg = times[b] * f;
    te[t] = sinf(arg);
    te[t + HALFD] = cosf(arg);
  }
  __syncthreads();
  float acc = 0.f;
#pragma unroll 8
  for (int k = 0; k < TDIM; ++k) acc += te[k] * W1[(1 + k) * HH + t];
  tproj[b * HH + t] = acc;
}

// ---- K3: pp = dis_i*(As@dd), qq = dis_i*(As@dis) via bitmap ctz-walk.
__global__ __launch_bounds__(512) void k_pq(const unsigned int* __restrict__ bits,
    const float* __restrict__ dis, const float* __restrict__ dd,
    float* __restrict__ pp, float* __restrict__ qq, int b0) {
  int bl = blockIdx.x, bg = b0 + bl, t = threadIdx.x;
  __shared__ float sd[NN], su[NN];
  for (int j = t; j < NN; j += 512) { sd[j] = dis[bg * NN + j]; su[j] = dd[bg * NN + j]; }
  __syncthreads();
  if (t >= NN) return;
  const uint4* bp = (const uint4*)(bits + ((size_t)bl * NN + t) * BITW);
  uint4 qa = bp[0], qb = bp[1], qc = bp[2];
  unsigned int wr[13] = {qa.x, qa.y, qa.z, qa.w, qb.x, qb.y, qb.z, qb.w,
                         qc.x, qc.y, qc.z, qc.w, ((const unsigned int*)bp)[12]};
  float ps = 0.f, qs = 0.f;
#pragma unroll
  for (int w = 0; w < 13; ++w) {
    unsigned int u = wr[w];
    int base = w * 32;
    while (u) {
      int j = base + __builtin_ctz(u);
      u &= u - 1;
      ps += su[j]; qs += sd[j];
    }
  }
  float d = sd[t];
  pp[bg * NN + t] = d * ps;
  qq[bg * NN + t] = d * qs;
}

// ---- K4: W2 -> bf16 transposed padded [256 n][264 k]
__global__ __launch_bounds__(256) void k_w2t(const float* __restrict__ W2,
                                             short* __restrict__ W2Tg) {
  int n = blockIdx.x, k = threadIdx.x;
  W2Tg[n * W2PAD + k] = f2bf_rne(W2[k * HH + n]);
}

// ---- K5: y2T[n][m] = dis_m * (g1 @ W2)[m][n], g1 on the fly (UNCHANGED from R3).
__global__ __launch_bounds__(320) void k_gemm(const short* __restrict__ W2Tg,
    const float* __restrict__ W1, const float* __restrict__ b1,
    const float* __restrict__ tproj, const float* __restrict__ dis,
    const float* __restrict__ pp, const float* __restrict__ qq,
    short* __restrict__ y2T, int b0) {
  extern __shared__ short lds[];  // 128*264*2 = 67584 B; reused as bounce [128][88]
  int t = threadIdx.x;
  int wv = t >> 6, lane = t & 63, l15 = lane & 15, l4 = lane >> 4;
  int bl = blockIdx.x / 5, mt = blockIdx.x % 5;
  int ny = blockIdx.y;
  int bg = b0 + bl;
  int m0 = mt * 80;

  {
    const short* gsrc = W2Tg + (size_t)ny * 128 * W2PAD;
#pragma unroll
    for (int r = 0; r < 14; ++r) {
      int idx = r * 320 + t;
      if (idx < 128 * W2PAD / 8) *(short8*)(lds + idx * 8) = *(const short8*)(gsrc + idx * 8);
    }
  }

  int arow = m0 + wv * 16 + l15;
  int gnode = bg * NN + arow;
  float ppv = pp[gnode], qqv = qq[gnode];
  const float* tpr = tproj + bg * HH;

  f32x4 acc[8];
#pragma unroll
  for (int f = 0; f < 8; ++f) acc[f] = (f32x4){0.f, 0.f, 0.f, 0.f};

  __syncthreads();

#pragma unroll 2
  for (int k0 = 0; k0 < 8; ++k0) {
    int kk = k0 * 32 + l4 * 8;
    float4 w1a = *(const float4*)(W1 + kk), w1b = *(const float4*)(W1 + kk + 4);
    float4 b1a = *(const float4*)(b1 + kk), b1b = *(const float4*)(b1 + kk + 4);
    float4 tpa = *(const float4*)(tpr + kk), tpb = *(const float4*)(tpr + kk + 4);
    short8 af;
    af[0] = f2bf_trunc(fmaxf(ppv * w1a.x + qqv * tpa.x + b1a.x, 0.f));
    af[1] = f2bf_trunc(fmaxf(ppv * w1a.y + qqv * tpa.y + b1a.y, 0.f));
    af[2] = f2bf_trunc(fmaxf(ppv * w1a.z + qqv * tpa.z + b1a.z, 0.f));
    af[3] = f2bf_trunc(fmaxf(ppv * w1a.w + qqv * tpa.w + b1a.w, 0.f));
    af[4] = f2bf_trunc(fmaxf(ppv * w1b.x + qqv * tpb.x + b1b.x, 0.f));
    af[5] = f2bf_trunc(fmaxf(ppv * w1b.y + qqv * tpb.y + b1b.y, 0.f));
    af[6] = f2bf_trunc(fmaxf(ppv * w1b.z + qqv * tpb.z + b1b.z, 0.f));
    af[7] = f2bf_trunc(fmaxf(ppv * w1b.w + qqv * tpb.w + b1b.w, 0.f));
#pragma unroll
    for (int f = 0; f < 8; ++f) {
      short8 bf = *(const short8*)(lds + (f * 16 + l15) * W2PAD + kk);
      acc[f] = __builtin_amdgcn_mfma_f32_16x16x32_bf16(af, bf, acc[f], 0, 0, 0);
    }
  }

  float dis4[4];
#pragma unroll
  for (int rr = 0; rr < 4; ++rr) dis4[rr] = dis[bg * NN + m0 + wv * 16 + l4 * 4 + rr];

  __syncthreads();  // all waves done reading W2T
  short* bb = lds;  // [128 n][88 m] bf16 bounce (transposed)
#pragma unroll
  for (int f = 0; f < 8; ++f) {
    short4v pk;
#pragma unroll
    for (int rr = 0; rr < 4; ++rr) pk[rr] = f2bf_trunc(dis4[rr] * acc[f][rr]);
    *(short4v*)(&bb[(f * 16 + l15) * 88 + wv * 16 + l4 * 4]) = pk;
  }
  __syncthreads();
  short* ybase = y2T + (size_t)bl * HH * KP + (size_t)ny * 128 * KP + m0;
#pragma unroll
  for (int r = 0; r < 4; ++r) {
    int idx = r * 320 + t;  // 1280 chunks of 16B
    int n = idx / 10, c = idx % 10;
    short8 v = *(const short8*)(&bb[n * 88 + c * 8]);
    *(short8*)(ybase + (size_t)n * KP + c * 8) = v;
  }
}

// ---- K5b: zero y2T K-pad cols [*, *, 400:416]
__global__ __launch_bounds__(256) void k_zpad(short* __restrict__ y2T) {
  int bl = blockIdx.x, t = threadIdx.x;
  short8 z = {};
  *(short8*)(y2T + (size_t)bl * HH * KP + (size_t)t * KP + 400) = z;
  *(short8*)(y2T + (size_t)bl * HH * KP + (size_t)t * KP + 408) = z;
}

// ---- K6: aggregation GEMM from BITMAP + relu + pool.
//      Grid (CB, 2): block = (graph, 128-n half). 8 waves = 2 wm x 4 wn.
//      Thread t<400 holds bitmap row t in 13 regs; per K-step expands one
//      word into bf16 LDS tile (double-buffered); B-frags reg-prefetched
//      straight from global (y2T read exactly once per graph).
__global__ __launch_bounds__(512) void k_agg(const unsigned int* __restrict__ bits,
    const short* __restrict__ y2T, const float* __restrict__ dis,
    const float* __restrict__ b2, float* __restrict__ poolP, int b0) {
  __shared__ short asb[2][416][40];   // 66560 B, stride 80B = odd-quad
  __shared__ float pool[4][2][32];
  int t = threadIdx.x, wv = t >> 6, lane = t & 63, l15 = lane & 15, l4 = lane >> 4;
  int wm = wv >> 2, wn = wv & 3;
  int bl = blockIdx.x, by = blockIdx.y, bg = b0 + bl;

  unsigned int w[13];
  if (t < NN) {
    const uint4* bp = (const uint4*)(bits + ((size_t)bl * NN + t) * BITW);
    uint4 qa = bp[0], qb = bp[1], qc = bp[2];
    w[0] = qa.x; w[1] = qa.y; w[2] = qa.z; w[3] = qa.w;
    w[4] = qb.x; w[5] = qb.y; w[6] = qb.z; w[7] = qb.w;
    w[8] = qc.x; w[9] = qc.y; w[10] = qc.z; w[11] = qc.w;
    w[12] = ((const unsigned int*)bp)[12];
  } else {
#pragma unroll
    for (int i = 0; i < 13; ++i) w[i] = 0u;
  }
  if (t >= NN && t < 416) {  // zero pad rows in both buffers (written once)
    short8 z = {};
#pragma unroll
    for (int bu = 0; bu < 2; ++bu)
#pragma unroll
      for (int c = 0; c < 5; ++c) *(short8*)(&asb[bu][t][c * 8]) = z;
  }

  const short* yb = y2T + (size_t)bl * HH * KP +
                    (size_t)(by * 128 + wn * 32 + l15) * KP + l4 * 8;

#define EXPAND_TO(BUFIDX, WORD)                                          \
  do {                                                                   \
    unsigned int _w = (WORD);                                            \
    _Pragma("unroll") for (int c = 0; c < 4; ++c) {                      \
      short8 e;                                                          \
      _Pragma("unroll") for (int bb2 = 0; bb2 < 8; ++bb2)                \
          e[bb2] = ((_w >> (c * 8 + bb2)) & 1u) ? (short)0x3F80 : (short)0; \
      *(short8*)(&asb[BUFIDX][t][c * 8]) = e;                            \
    }                                                                    \
  } while (0)

  if (t < NN) EXPAND_TO(0, w[0]);
  short8 b0c = *(const short8*)(yb);
  short8 b1c = *(const short8*)(yb + 16 * KP);
  __syncthreads();

  f32x4 acc[13][2];
#pragma unroll
  for (int mf = 0; mf < 13; ++mf) {
    acc[mf][0] = (f32x4){0.f, 0.f, 0.f, 0.f};
    acc[mf][1] = (f32x4){0.f, 0.f, 0.f, 0.f};
  }
  const int MF = (wm == 0) ? 13 : 12;  // wm=1 rows 208..399 (mf 12 = pad)
  int mrow = wm * 208 + l15;

#pragma unroll
  for (int ks = 0; ks < 13; ++ks) {
    int cur = ks & 1;
    short8 b0n = {}, b1n = {};
    if (ks < 12) {
      b0n = *(const short8*)(yb + (ks + 1) * 32);
      b1n = *(const short8*)(yb + 16 * KP + (ks + 1) * 32);
      if (t < NN) EXPAND_TO(cur ^ 1, w[ks + 1]);
    }
#pragma unroll
    for (int mf = 0; mf < 13; ++mf) {
      if (mf < MF) {
        short8 af = *(const short8*)(&asb[cur][mrow + mf * 16][l4 * 8]);
        acc[mf][0] = __builtin_amdgcn_mfma_f32_16x16x32_bf16(af, b0c, acc[mf][0], 0, 0, 0);
        acc[mf][1] = __builtin_amdgcn_mfma_f32_16x16x32_bf16(af, b1c, acc[mf][1], 0, 0, 0);
      }
    }
    b0c = b0n; b1c = b1n;
    __syncthreads();
  }
#undef EXPAND_TO

  // epilogue: s(n) = sum_m relu(dis_m * C[m][n] + b2[n]) over this wave's m-range
#pragma unroll
  for (int nf = 0; nf < 2; ++nf) {
    float b2v = b2[by * 128 + wn * 32 + nf * 16 + l15];
    float s = 0.f;
#pragma unroll
    for (int mf = 0; mf < 13; ++mf) {
      if (mf < MF) {
        int m0 = wm * 208 + mf * 16 + l4 * 4;
        float4 d4 = *(const float4*)(dis + bg * NN + m0);
        s += fmaxf(d4.x * acc[mf][nf][0] + b2v, 0.f)
           + fmaxf(d4.y * acc[mf][nf][1] + b2v, 0.f)
           + fmaxf(d4.z * acc[mf][nf][2] + b2v, 0.f)
           + fmaxf(d4.w * acc[mf][nf][3] + b2v, 0.f);
      }
    }
    s += __shfl_xor(s, 16);
    s += __shfl_xor(s, 32);
    if (l4 == 0) pool[wn][wm][nf * 16 + l15] = s;
  }
  __syncthreads();
  if (t < 128) {
    float v = pool[t >> 5][0][t & 31] + pool[t >> 5][1][t & 31];
    poolP[(size_t)bg * HH + by * 128 + t] = v;
  }
}

// ---- K7: logits = (poolP/400) @ Wlin + blin
__global__ __launch_bounds__(256) void k_out(
    const float* __restrict__ poolP, const float* __restrict__ Wlin,
    const float* __restrict__ blin, float* __restrict__ out) {
  int b = blockIdx.x, t = threadIdx.x;
  __shared__ float ps[HH];
  ps[t] = poolP[(size_t)b * HH + t] * (1.f / 400.f);
  __syncthreads();
#pragma unroll
  for (int c = 0; c < 4; ++c) {
    int o = t + c * 256;
    if (o < OUTD) {
      float acc = blin[o];
#pragma unroll 8
      for (int h = 0; h < HH; ++h) acc += ps[h] * Wlin[h * OUTD + o];
      out[b * OUTD + o] = acc;
    }
  }
}

extern "C" void kernel_launch(void* const* d_in, const int* in_sizes, int n_in,
                              void* d_out, int out_size, void* d_ws, size_t ws_size,
                              hipStream_t stream) {
  const float* adj   = (const float*)d_in[0];
  const float* times = (const float*)d_in[1];
  const float* W1    = (const float*)d_in[2];
  const float* b1    = (const float*)d_in[3];
  const float* W2    = (const float*)d_in[4];
  const float* b2    = (const float*)d_in[5];
  const float* Wlin  = (const float*)d_in[6];
  const float* blin  = (const float*)d_in[7];
  float* out = (float*)d_out;

  char* ws = (char*)d_ws;
  size_t off = 0;
  auto alloc = [&](size_t bytes) -> void* {
    void* ptr = ws + off;
    off = (off + bytes + 255) & ~(size_t)255;
    return ptr;
  };
  float* dis    = (float*)alloc((size_t)BATCH * NN * 4);
  float* dd     = (float*)alloc((size_t)BATCH * NN * 4);
  float* pp     = (float*)alloc((size_t)BATCH * NN * 4);
  float* qq     = (float*)alloc((size_t)BATCH * NN * 4);
  float* tproj  = (float*)alloc((size_t)BATCH * HH * 4);
  float* poolP  = (float*)alloc((size_t)BATCH * HH * 4);
  short* W2Tg   = (short*)alloc((size_t)HH * W2PAD * 2);
  size_t small = off;

  int CB = 8;
  const int cand[6] = {256, 128, 64, 32, 16, 8};
  size_t per_graph = (size_t)NN * BITW * 4 + (size_t)HH * KP * 2;
  for (int ci = 0; ci < 6; ++ci) {
    if (small + (size_t)cand[ci] * per_graph + 512 <= ws_size) { CB = cand[ci]; break; }
  }
  unsigned int* bits = (unsigned int*)alloc((size_t)CB * NN * BITW * 4);
  short* y2T = (short*)alloc((size_t)CB * HH * KP * 2);

  k_temb<<<BATCH, 256, 0, stream>>>(times, W1, tproj);
  k_w2t<<<HH, 256, 0, stream>>>(W2, W2Tg);

  for (int b0 = 0; b0 < BATCH; b0 += CB) {
    k_prep<<<dim3(CB, 25), 256, 0, stream>>>(adj, bits, dis, dd, b0);
    k_pq<<<CB, 512, 0, stream>>>(bits, dis, dd, pp, qq, b0);
    k_gemm<<<dim3(CB * 5, 2), 320, 128 * W2PAD * 2, stream>>>(
        W2Tg, W1, b1, tproj, dis, pp, qq, y2T, b0);
    k_zpad<<<CB, 256, 0, stream>>>(y2T);
    k_agg<<<dim3(CB, 2), 512, 0, stream>>>(bits, y2T, dis, b2, poolP, b0);
  }
  k_out<<<BATCH, 256, 0, stream>>>(poolP, Wlin, blin, out);
}